// Round 7
// baseline (305.451 us; speedup 1.0000x reference)
//
#include <hip/hip_runtime.h>

#define CIN 64
#define COUT 32

typedef __attribute__((ext_vector_type(8))) short bf16x8;
typedef __attribute__((ext_vector_type(4))) float f32x4;

__device__ inline ushort f2bf(float x) {
    union { float f; unsigned u; } v; v.f = x;
    unsigned r = v.u + 0x7fff + ((v.u >> 16) & 1);   // RNE
    return (ushort)(r >> 16);
}

// Zero the fp16 accumulator buffer (uint4 = 8 halves per thread).
__global__ __launch_bounds__(256) void zero16_kernel(uint4* __restrict__ p, int n16)
{
    int i = blockIdx.x * blockDim.x + threadIdx.x;
    if (i < n16) p[i] = uint4{0u, 0u, 0u, 0u};
}

// Fused MFMA gather-GEMM -> LDS lane-transpose -> packed v2f16 atomic scatter.
// B even/odd interleave: acc0[r] = channel 2*col, acc1[r] = 2*col+1 (verified).
// After the 16x16 transpose each lane owns 4 consecutive colpairs of ONE output
// row, so a wave instruction spreads its 64 atomics over 16 distinct 64B lines
// (4 ops/line) instead of 4 lines (16 ops/line).
__global__ __launch_bounds__(256) void mfma_scatter_pk2_kernel(
    const float* __restrict__ feats,     // [N_IN][64] fp32
    const float* __restrict__ weight,    // [K][64][32] fp32
    const int* __restrict__ in_idx,
    const int* __restrict__ out_idx,
    ushort* __restrict__ outh,           // [n_out][32] fp16 accumulator
    int P, int ntiles, int waves_per_k)
{
    __shared__ unsigned ldsT[4 * 320];   // 4 waves x (16 rows x 20 dwords)

    const int k    = blockIdx.y;
    const int lane = threadIdx.x & 63;
    const int wblk = threadIdx.x >> 6;
    const int wav  = blockIdx.x * 4 + wblk;
    const int col  = lane & 15;
    const int kch  = lane >> 4;          // 0..3
    unsigned* __restrict__ slab = &ldsT[wblk * 320];

    // B fragments: bfrag[ks][h] covers k = ks*32+kch*8+e, out channel 2*col+h.
    bf16x8 bfrag[2][2];
    const float* __restrict__ Wk = weight + (long)k * CIN * COUT;
    #pragma unroll
    for (int ks = 0; ks < 2; ++ks)
        #pragma unroll
        for (int h = 0; h < 2; ++h) {
            bf16x8 t;
            #pragma unroll
            for (int e = 0; e < 8; ++e)
                t[e] = (short)f2bf(Wk[(ks * 32 + kch * 8 + e) * COUT + 2 * col + h]);
            bfrag[ks][h] = t;
        }

    // Post-transpose identity of this lane: one row, 4 consecutive colpairs.
    const int r_abs = lane & 15;         // row within tile
    const int cbase = (lane >> 4) * 4;   // first colpair

    const int base = k * P;
    for (int tile = wav; tile < ntiles; tile += waves_per_k) {
        const int p0 = tile << 4;

        // Gather A: lane's M-row = pair p0+col; 4 x 16B fp32 loads, cvt in-reg.
        const int pA  = min(p0 + col, P - 1);
        const int row = in_idx[base + pA];
        const float* __restrict__ ar = feats + (long)row * CIN + kch * 8;
        float4 f0 = *reinterpret_cast<const float4*>(ar);
        float4 f1 = *reinterpret_cast<const float4*>(ar + 4);
        float4 f2 = *reinterpret_cast<const float4*>(ar + 32);
        float4 f3 = *reinterpret_cast<const float4*>(ar + 36);

        bf16x8 a0, a1;
        a0[0] = (short)f2bf(f0.x); a0[1] = (short)f2bf(f0.y);
        a0[2] = (short)f2bf(f0.z); a0[3] = (short)f2bf(f0.w);
        a0[4] = (short)f2bf(f1.x); a0[5] = (short)f2bf(f1.y);
        a0[6] = (short)f2bf(f1.z); a0[7] = (short)f2bf(f1.w);
        a1[0] = (short)f2bf(f2.x); a1[1] = (short)f2bf(f2.y);
        a1[2] = (short)f2bf(f2.z); a1[3] = (short)f2bf(f2.w);
        a1[4] = (short)f2bf(f3.x); a1[5] = (short)f2bf(f3.y);
        a1[6] = (short)f2bf(f3.z); a1[7] = (short)f2bf(f3.w);

        f32x4 acc0 = {0.f, 0.f, 0.f, 0.f};
        f32x4 acc1 = {0.f, 0.f, 0.f, 0.f};
        acc0 = __builtin_amdgcn_mfma_f32_16x16x32_bf16(a0, bfrag[0][0], acc0, 0, 0, 0);
        acc0 = __builtin_amdgcn_mfma_f32_16x16x32_bf16(a1, bfrag[1][0], acc0, 0, 0, 0);
        acc1 = __builtin_amdgcn_mfma_f32_16x16x32_bf16(a0, bfrag[0][1], acc1, 0, 0, 0);
        acc1 = __builtin_amdgcn_mfma_f32_16x16x32_bf16(a1, bfrag[1][1], acc1, 0, 0, 0);

        // Pack v2f16 and write to LDS at [row][colpair] (stride 20 dwords).
        #pragma unroll
        for (int r = 0; r < 4; ++r) {
            union { _Float16 h[2]; unsigned u; } pk;
            pk.h[0] = (_Float16)acc0[r];
            pk.h[1] = (_Float16)acc1[r];
            slab[(4 * kch + r) * 20 + col] = pk.u;
        }

        // Transposed read: this lane's row, 4 consecutive colpairs (16B aligned).
        uint4 vals = *reinterpret_cast<const uint4*>(&slab[r_abs * 20 + cbase]);

        const int prow = p0 + r_abs;
        if (prow < P) {
            const int orow = out_idx[base + prow];
            unsigned long long addr = (unsigned long long)outh
                                    + (unsigned long long)orow * (COUT * 2)
                                    + (unsigned)(cbase * 4);
            asm volatile("global_atomic_pk_add_f16 %0, %1, off"
                         :: "v"(addr), "v"(vals.x) : "memory");
            asm volatile("global_atomic_pk_add_f16 %0, %1, off offset:4"
                         :: "v"(addr), "v"(vals.y) : "memory");
            asm volatile("global_atomic_pk_add_f16 %0, %1, off offset:8"
                         :: "v"(addr), "v"(vals.z) : "memory");
            asm volatile("global_atomic_pk_add_f16 %0, %1, off offset:12"
                         :: "v"(addr), "v"(vals.w) : "memory");
        }
    }
}

// out[i] = fp32(outh[i]) + bias[ch], 4 channels per thread.
__global__ __launch_bounds__(256) void finalize_kernel(
    const unsigned* __restrict__ outh_u, const float* __restrict__ bias,
    float* __restrict__ out, int n4)
{
    int i = blockIdx.x * blockDim.x + threadIdx.x;
    if (i < n4) {
        unsigned u0 = outh_u[2 * i], u1 = outh_u[2 * i + 1];
        int ch = (i * 4) & (COUT - 1);
        union { unsigned u; _Float16 h[2]; } a, b;
        a.u = u0; b.u = u1;
        float4 o;
        o.x = (float)a.h[0] + bias[ch + 0];
        o.y = (float)a.h[1] + bias[ch + 1];
        o.z = (float)b.h[0] + bias[ch + 2];
        o.w = (float)b.h[1] + bias[ch + 3];
        reinterpret_cast<float4*>(out)[i] = o;
    }
}

// ============ Fallback (R2 atomic path, no workspace) ============

__global__ __launch_bounds__(256) void bias_init_kernel(
    float* __restrict__ out, const float* __restrict__ bias, int total)
{
    int i = (blockIdx.x * blockDim.x + threadIdx.x) * 4;
    if (i < total) {
        int ch = i & (COUT - 1);
        float4 b;
        b.x = bias[ch + 0]; b.y = bias[ch + 1];
        b.z = bias[ch + 2]; b.w = bias[ch + 3];
        *reinterpret_cast<float4*>(out + i) = b;
    }
}

__global__ __launch_bounds__(256) void scatter_gemm_kernel(
    const float* __restrict__ feats,
    const float* __restrict__ weight,
    const int* __restrict__ in_idx,
    const int* __restrict__ out_idx,
    float* __restrict__ out,
    int P, int n_groups)
{
    const int k        = blockIdx.y;
    const int lane     = threadIdx.x & 31;
    const int group_id = blockIdx.x * (blockDim.x >> 5) + (threadIdx.x >> 5);

    float w[CIN];
    const float* __restrict__ Wk = weight + (long)k * CIN * COUT;
    #pragma unroll
    for (int c = 0; c < CIN; ++c) w[c] = Wk[c * COUT + lane];

    const int base    = k * P;
    const int nchunks = (P + 31) >> 5;
    for (int ch = group_id; ch < nchunks; ch += n_groups) {
        const int p0 = ch << 5;
        const int n  = min(32, P - p0);
        int my_in = 0, my_out = 0;
        if (lane < n) {
            my_in  = in_idx[base + p0 + lane];
            my_out = out_idx[base + p0 + lane];
        }
        #pragma unroll 4
        for (int j = 0; j < n; ++j) {
            const int in = __shfl(my_in,  j, 32);
            const int o  = __shfl(my_out, j, 32);
            const float4* __restrict__ fr =
                reinterpret_cast<const float4*>(feats + (long)in * CIN);
            float acc = 0.0f;
            #pragma unroll
            for (int c4 = 0; c4 < CIN / 4; ++c4) {
                float4 f = fr[c4];
                acc += f.x * w[4 * c4 + 0];
                acc += f.y * w[4 * c4 + 1];
                acc += f.z * w[4 * c4 + 2];
                acc += f.w * w[4 * c4 + 3];
            }
            atomicAdd(out + (long)o * COUT + lane, acc);
        }
    }
}

// ============ launch ============

extern "C" void kernel_launch(void* const* d_in, const int* in_sizes, int n_in,
                              void* d_out, int out_size, void* d_ws, size_t ws_size,
                              hipStream_t stream) {
    const float* feats   = (const float*)d_in[0];
    const float* weight  = (const float*)d_in[1];
    const float* bias    = (const float*)d_in[2];
    const int*   in_idx  = (const int*)d_in[3];
    const int*   out_idx = (const int*)d_in[4];
    float*       out     = (float*)d_out;

    const int K = in_sizes[1] / (CIN * COUT);  // 27
    const int P = in_sizes[3] / K;             // 50000

    // ws: fp16 accumulator only.
    size_t need = (size_t)out_size * 2;

    if (need > ws_size || (out_size & 7) != 0) {
        int total4 = out_size / 4;
        bias_init_kernel<<<(total4 + 255) / 256, 256, 0, stream>>>(out, bias, out_size);
        const int blocks_x = 96;
        const int n_groups = blocks_x * (256 / 32);
        dim3 grid(blocks_x, K);
        scatter_gemm_kernel<<<grid, 256, 0, stream>>>(feats, weight, in_idx, out_idx,
                                                      out, P, n_groups);
        return;
    }

    ushort* outh = (ushort*)d_ws;

    // Zero fp16 accumulator.
    {
        int n16 = (out_size * 2) / 16;
        zero16_kernel<<<(n16 + 255) / 256, 256, 0, stream>>>((uint4*)outh, n16);
    }

    // Fused gather-GEMM + transposed pk-f16 atomic scatter.
    {
        const int ntiles      = (P + 15) / 16;
        const int blocks_x    = 196;
        const int waves_per_k = blocks_x * 4;
        dim3 grid(blocks_x, K);
        mfma_scatter_pk2_kernel<<<grid, 256, 0, stream>>>(feats, weight, in_idx,
                                                          out_idx, outh, P, ntiles,
                                                          waves_per_k);
    }

    // Finalize: widen + bias.
    finalize_kernel<<<(out_size / 4 + 255) / 256, 256, 0, stream>>>(
        (const unsigned*)outh, bias, out, out_size / 4);
}

// Round 8
// 104.169 us; speedup vs baseline: 2.9323x; 2.9323x over previous
//
#include <hip/hip_runtime.h>

#define CIN 64
#define COUT 32

typedef __attribute__((ext_vector_type(8))) short bf16x8;
typedef __attribute__((ext_vector_type(4))) float f32x4;

__device__ inline ushort f2bf(float x) {
    union { float f; unsigned u; } v; v.f = x;
    unsigned r = v.u + 0x7fff + ((v.u >> 16) & 1);   // RNE
    return (ushort)(r >> 16);
}

// Zero the fp16 accumulator buffer (uint4 = 8 halves per thread).
__global__ __launch_bounds__(256) void zero16_kernel(uint4* __restrict__ p, int n16)
{
    int i = blockIdx.x * blockDim.x + threadIdx.x;
    if (i < n16) p[i] = uint4{0u, 0u, 0u, 0u};
}

// Fused MFMA gather-GEMM -> packed v2f16 atomic scatter (R6 pattern: each
// instruction's 16 same-line lanes are at contiguous 4B stride -> HW merges
// into ONE 64B line-RMW per output row; 1 line-RMW per pair total).
// fp32 feats gathered directly, cvt to bf16 in-register (kills cvt kernel).
__global__ __launch_bounds__(256) void mfma_scatter_pk_kernel(
    const float* __restrict__ feats,     // [N_IN][64] fp32
    const float* __restrict__ weight,    // [K][64][32] fp32
    const int* __restrict__ in_idx,
    const int* __restrict__ out_idx,
    ushort* __restrict__ outh,           // [n_out][32] fp16 accumulator
    int P, int ntiles, int waves_per_k)
{
    const int k    = blockIdx.y;
    const int lane = threadIdx.x & 63;
    const int wav  = blockIdx.x * (blockDim.x >> 6) + (threadIdx.x >> 6);
    const int col  = lane & 15;
    const int kch  = lane >> 4;          // 0..3

    // B fragments: bfrag[ks][h] covers k = ks*32+kch*8+e, out channel 2*col+h.
    bf16x8 bfrag[2][2];
    const float* __restrict__ Wk = weight + (long)k * CIN * COUT;
    #pragma unroll
    for (int ks = 0; ks < 2; ++ks)
        #pragma unroll
        for (int h = 0; h < 2; ++h) {
            bf16x8 t;
            #pragma unroll
            for (int e = 0; e < 8; ++e)
                t[e] = (short)f2bf(Wk[(ks * 32 + kch * 8 + e) * COUT + 2 * col + h]);
            bfrag[ks][h] = t;
        }

    const int base = k * P;
    for (int tile = wav; tile < ntiles; tile += waves_per_k) {
        const int p0 = tile << 4;
        const int pA = min(p0 + col, P - 1);

        // Coalesced index loads (lanes 0..15 cover the tile; dup x4 groups).
        const int row   = in_idx[base + pA];
        const int my_o  = out_idx[base + pA];

        // Gather A: 4 x 16B fp32 loads, cvt to bf16 in-register.
        const float* __restrict__ ar = feats + (long)row * CIN + kch * 8;
        float4 f0 = *reinterpret_cast<const float4*>(ar);
        float4 f1 = *reinterpret_cast<const float4*>(ar + 4);
        float4 f2 = *reinterpret_cast<const float4*>(ar + 32);
        float4 f3 = *reinterpret_cast<const float4*>(ar + 36);

        bf16x8 a0, a1;
        a0[0] = (short)f2bf(f0.x); a0[1] = (short)f2bf(f0.y);
        a0[2] = (short)f2bf(f0.z); a0[3] = (short)f2bf(f0.w);
        a0[4] = (short)f2bf(f1.x); a0[5] = (short)f2bf(f1.y);
        a0[6] = (short)f2bf(f1.z); a0[7] = (short)f2bf(f1.w);
        a1[0] = (short)f2bf(f2.x); a1[1] = (short)f2bf(f2.y);
        a1[2] = (short)f2bf(f2.z); a1[3] = (short)f2bf(f2.w);
        a1[4] = (short)f2bf(f3.x); a1[5] = (short)f2bf(f3.y);
        a1[6] = (short)f2bf(f3.z); a1[7] = (short)f2bf(f3.w);

        f32x4 acc0 = {0.f, 0.f, 0.f, 0.f};
        f32x4 acc1 = {0.f, 0.f, 0.f, 0.f};
        acc0 = __builtin_amdgcn_mfma_f32_16x16x32_bf16(a0, bfrag[0][0], acc0, 0, 0, 0);
        acc0 = __builtin_amdgcn_mfma_f32_16x16x32_bf16(a1, bfrag[1][0], acc0, 0, 0, 0);
        acc1 = __builtin_amdgcn_mfma_f32_16x16x32_bf16(a0, bfrag[0][1], acc1, 0, 0, 0);
        acc1 = __builtin_amdgcn_mfma_f32_16x16x32_bf16(a1, bfrag[1][1], acc1, 0, 0, 0);

        // Scatter: row of acc r = pair p0 + kch*4 + r; its out row comes from
        // the lane that loaded it (lane kch*4+r) via bpermute.
        #pragma unroll
        for (int r = 0; r < 4; ++r) {
            const int prow = p0 + kch * 4 + r;
            const int orow = __shfl(my_o, kch * 4 + r, 64);
            if (prow < P) {
                union { _Float16 h[2]; unsigned u; } pk;
                pk.h[0] = (_Float16)acc0[r];
                pk.h[1] = (_Float16)acc1[r];
                const ushort* dst = outh + (long)orow * COUT + 2 * col;
                asm volatile("global_atomic_pk_add_f16 %0, %1, off"
                             :: "v"((unsigned long long)dst), "v"(pk.u)
                             : "memory");
            }
        }
    }
}

// out[i] = fp32(outh[i]) + bias[ch], 4 channels per thread.
__global__ __launch_bounds__(256) void finalize_kernel(
    const unsigned* __restrict__ outh_u, const float* __restrict__ bias,
    float* __restrict__ out, int n4)
{
    int i = blockIdx.x * blockDim.x + threadIdx.x;
    if (i < n4) {
        unsigned u0 = outh_u[2 * i], u1 = outh_u[2 * i + 1];
        int ch = (i * 4) & (COUT - 1);
        union { unsigned u; _Float16 h[2]; } a, b;
        a.u = u0; b.u = u1;
        float4 o;
        o.x = (float)a.h[0] + bias[ch + 0];
        o.y = (float)a.h[1] + bias[ch + 1];
        o.z = (float)b.h[0] + bias[ch + 2];
        o.w = (float)b.h[1] + bias[ch + 3];
        reinterpret_cast<float4*>(out)[i] = o;
    }
}

// ============ Fallback (R2 atomic path, no workspace) ============

__global__ __launch_bounds__(256) void bias_init_kernel(
    float* __restrict__ out, const float* __restrict__ bias, int total)
{
    int i = (blockIdx.x * blockDim.x + threadIdx.x) * 4;
    if (i < total) {
        int ch = i & (COUT - 1);
        float4 b;
        b.x = bias[ch + 0]; b.y = bias[ch + 1];
        b.z = bias[ch + 2]; b.w = bias[ch + 3];
        *reinterpret_cast<float4*>(out + i) = b;
    }
}

__global__ __launch_bounds__(256) void scatter_gemm_kernel(
    const float* __restrict__ feats,
    const float* __restrict__ weight,
    const int* __restrict__ in_idx,
    const int* __restrict__ out_idx,
    float* __restrict__ out,
    int P, int n_groups)
{
    const int k        = blockIdx.y;
    const int lane     = threadIdx.x & 31;
    const int group_id = blockIdx.x * (blockDim.x >> 5) + (threadIdx.x >> 5);

    float w[CIN];
    const float* __restrict__ Wk = weight + (long)k * CIN * COUT;
    #pragma unroll
    for (int c = 0; c < CIN; ++c) w[c] = Wk[c * COUT + lane];

    const int base    = k * P;
    const int nchunks = (P + 31) >> 5;
    for (int ch = group_id; ch < nchunks; ch += n_groups) {
        const int p0 = ch << 5;
        const int n  = min(32, P - p0);
        int my_in = 0, my_out = 0;
        if (lane < n) {
            my_in  = in_idx[base + p0 + lane];
            my_out = out_idx[base + p0 + lane];
        }
        #pragma unroll 4
        for (int j = 0; j < n; ++j) {
            const int in = __shfl(my_in,  j, 32);
            const int o  = __shfl(my_out, j, 32);
            const float4* __restrict__ fr =
                reinterpret_cast<const float4*>(feats + (long)in * CIN);
            float acc = 0.0f;
            #pragma unroll
            for (int c4 = 0; c4 < CIN / 4; ++c4) {
                float4 f = fr[c4];
                acc += f.x * w[4 * c4 + 0];
                acc += f.y * w[4 * c4 + 1];
                acc += f.z * w[4 * c4 + 2];
                acc += f.w * w[4 * c4 + 3];
            }
            atomicAdd(out + (long)o * COUT + lane, acc);
        }
    }
}

// ============ launch ============

extern "C" void kernel_launch(void* const* d_in, const int* in_sizes, int n_in,
                              void* d_out, int out_size, void* d_ws, size_t ws_size,
                              hipStream_t stream) {
    const float* feats   = (const float*)d_in[0];
    const float* weight  = (const float*)d_in[1];
    const float* bias    = (const float*)d_in[2];
    const int*   in_idx  = (const int*)d_in[3];
    const int*   out_idx = (const int*)d_in[4];
    float*       out     = (float*)d_out;

    const int K = in_sizes[1] / (CIN * COUT);  // 27
    const int P = in_sizes[3] / K;             // 50000

    // ws: fp16 accumulator only.
    size_t need = (size_t)out_size * 2;

    if (need > ws_size || (out_size & 7) != 0) {
        int total4 = out_size / 4;
        bias_init_kernel<<<(total4 + 255) / 256, 256, 0, stream>>>(out, bias, out_size);
        const int blocks_x = 96;
        const int n_groups = blocks_x * (256 / 32);
        dim3 grid(blocks_x, K);
        scatter_gemm_kernel<<<grid, 256, 0, stream>>>(feats, weight, in_idx, out_idx,
                                                      out, P, n_groups);
        return;
    }

    ushort* outh = (ushort*)d_ws;

    // Zero fp16 accumulator.
    {
        int n16 = (out_size * 2) / 16;
        zero16_kernel<<<(n16 + 255) / 256, 256, 0, stream>>>((uint4*)outh, n16);
    }

    // Fused gather-GEMM + pk-f16 atomic scatter (line-merged pattern).
    {
        const int ntiles      = (P + 15) / 16;
        const int blocks_x    = 196;
        const int waves_per_k = blocks_x * 4;
        dim3 grid(blocks_x, K);
        mfma_scatter_pk_kernel<<<grid, 256, 0, stream>>>(feats, weight, in_idx,
                                                         out_idx, outh, P, ntiles,
                                                         waves_per_k);
    }

    // Finalize: widen + bias.
    finalize_kernel<<<(out_size / 4 + 255) / 256, 256, 0, stream>>>(
        (const unsigned*)outh, bias, out, out_size / 4);
}